// Round 5
// baseline (448.121 us; speedup 1.0000x reference)
//
#include <hip/hip_runtime.h>
#include <math.h>

#define WS 21
#define KWIN 43            // 2*WS+1
#define H 128
#define W 128
#define B 2
#define C 3
#define HW (H * W)
#define CHW (C * H * W)
#define NPIX (B * H * W)   // 32768
#define SIGMA_SPACE (1.0f / 98.0f)
#define NSPLIT 16
#define EXT 170            // W + 2*WS
#define SQ_THR 0.15f       // skip pairs with wr < e^{-7.5} (validated rounds 3-4, absmax 0)
// wr * d^0.8 = exp2(0.8*log2(d) - 50*log2(e)*sq); 50*log2(e) = 72.13475204
#define NEG_SC_LOG2E 72.1347520445f
#define SG 17.509290f      // sum_{k=-21..21} exp(-k^2/98), fp64-derived

__device__ __forceinline__ int reflect_idx(int t, int n) {
    if (t < 0) t = -t;
    if (t > n - 1) t = 2 * (n - 1) - t;
    return t;
}

// ---------------- K1: H-pass conv (256 thr) + Sobel mask (128 thr) + out zero ----------------
__global__ __launch_bounds__(384)
void prep_kernel(const float* __restrict__ orig,
                 const float* __restrict__ smooth,
                 float* __restrict__ Gh, float* __restrict__ Qh,
                 float* __restrict__ mask, float* __restrict__ out) {
    __shared__ float row[EXT], rsq[EXT], wt[KWIN];
    const int bid = blockIdx.x;      // bc*128 + h ; bc = b*3+c
    const int h   = bid & 127;
    const int bc  = bid >> 7;
    const int t   = threadIdx.x;
    if (bid == 0 && t == 0) out[0] = 0.f;
    if (t < KWIN) { int k = t - WS; wt[t] = __expf(-SIGMA_SPACE * (float)(k * k)); }
    const float* src = smooth + bc * HW + h * W;
    if (t < EXT) {
        float v = src[reflect_idx(t - WS, W)];
        row[t] = v; rsq[t] = v * v;
    }
    __syncthreads();
    if (t < 256) {
        const int w = t & 127;
        const float* buf = (t < 128) ? row : rsq;
        float acc = 0.f;
#pragma unroll
        for (int y = 0; y < KWIN; ++y) acc = fmaf(wt[y], buf[w + y], acc);
        ((t < 128) ? Gh : Qh)[bid * W + w] = acc;
    } else if (bc == 0 || bc == 3) {
        const int b = bc / 3;
        const int w = t - 256;
        const float* ob = orig   + b * CHW;
        const float* sb = smooth + b * CHW;
        int hm = reflect_idx(h - 1, H), hp = reflect_idx(h + 1, H);
        int wm = reflect_idx(w - 1, W), wp = reflect_idx(w + 1, W);
        float eo = 0.f, es = 0.f;
#pragma unroll
        for (int c = 0; c < C; ++c) {
            const float* po = ob + c * HW;
            const float* ps = sb + c * HW;
            {
                float a00 = po[hm * W + wm], a01 = po[hm * W + w], a02 = po[hm * W + wp];
                float a10 = po[h  * W + wm],                        a12 = po[h  * W + wp];
                float a20 = po[hp * W + wm], a21 = po[hp * W + w], a22 = po[hp * W + wp];
                float gx = (a02 - a00) + 2.f * (a12 - a10) + (a22 - a20);
                float gy = (a20 - a00) + 2.f * (a21 - a01) + (a22 - a02);
                eo += sqrtf(gx * gx + gy * gy);
            }
            {
                float a00 = ps[hm * W + wm], a01 = ps[hm * W + w], a02 = ps[hm * W + wp];
                float a10 = ps[h  * W + wm],                        a12 = ps[h  * W + wp];
                float a20 = ps[hp * W + wm], a21 = ps[hp * W + w], a22 = ps[hp * W + wp];
                float gx = (a02 - a00) + 2.f * (a12 - a10) + (a22 - a20);
                float gy = (a20 - a00) + 2.f * (a21 - a01) + (a22 - a02);
                es += sqrtf(gx * gx + gy * gy);
            }
        }
        float m = ((eo < 20.0f) && ((es - eo) > 10.0f)) ? 1.0f : 0.0f;
        mask[(b << 14) + (h << 7) + w] = m;
    }
}

// ---------------- K2: branchless bitmask screen + fused AL term + survivor recompute --------
__global__ __launch_bounds__(256, 6)
void smooth_loss_kernel(const float* __restrict__ orig,
                        const float* __restrict__ smooth,
                        const float* __restrict__ Gh, const float* __restrict__ Qh,
                        const float* __restrict__ mask,
                        float* __restrict__ out) {
    __shared__ float4 se4[340];     // [r*170 + e] = (o0,o1,o2,pad), reflection pre-applied
    __shared__ float red[4];

    const int t     = threadIdx.x;
    const int split = blockIdx.x & 15;
    const int rp    = (blockIdx.x >> 4) & 63;
    const int b     = blockIdx.x >> 10;
    const int h0    = rp * 2;
    const int w     = t & 127;
    const int half  = t >> 7;
    const int h     = h0 + half;
    const int lane  = t & 63;
    const int wave  = t >> 6;

    const float* ob = orig   + b * CHW;
    const float* sb = smooth + b * CHW;
    const float* GhB = Gh + b * 3 * HW;
    const float* QhB = Qh + b * 3 * HW;

    const int pix = (b << 14) + (h << 7) + w;
    const float m = mask[pix];
    const float thr_l = (m == 0.0f) ? SQ_THR : -1.0f;   // m==1 lanes never set bits

    float o0c, o1c, o2c, s0c, s1c, s2c;
    {
        int hw = h * W + w;
        o0c = ob[hw]; o1c = ob[HW + hw]; o2c = ob[2 * HW + hw];
        s0c = sb[hw]; s1c = sb[HW + hw]; s2c = sb[2 * HW + hw];
    }
    // AL constants (separable-Gaussian identity): per-channel s^2*Sg - 2s*Gh + Qh
    const float n0 = s0c * s0c * SG, n1 = s1c * s1c * SG, n2 = s2c * s2c * SG;
    const float tc0 = -2.f * s0c, tc1 = -2.f * s1c, tc2 = -2.f * s2c;

    // staging descriptors: element-1 = idx t, element-2 = idx t+256 (t<84); idx = r*170+e
    const int  e1r  = (t >= 170);
    const int  sc1  = reflect_idx((t - e1r * 170) - WS, W);
    const bool has2 = (t < 84);
    const int  sc2  = reflect_idx(t + 65, W);     // (t+256)-170-WS = t+65

    unsigned pmA[3] = {0u, 0u, 0u};   // yi 0..20  (bit at 20-yi)
    unsigned pmB[3] = {0u, 0u, 0u};   // yi 21..42 (bit at 42-yi)
    float accAL = 0.f, accS = 0.f;
    const int cb = half * EXT + w;

#pragma unroll
    for (int k = 0; k < 3; ++k) {
        const int xi = split + 16 * k;
        if (xi < KWIN) {                       // block-uniform: barriers safe
            const int x = xi - WS;
            const int hh0 = reflect_idx(h0 + x, H);
            const int hh1 = reflect_idx(h0 + 1 + x, H);
            __syncthreads();                   // previous screen done reading LDS
            // staging loads (orig only)
            const float* pA = ob + (e1r ? hh1 : hh0) * W + sc1;
            float a0 = pA[0], a1 = pA[HW], a2 = pA[2 * HW];
            float b0 = 0.f, b1 = 0.f, b2 = 0.f;
            if (has2) {
                const float* pB = ob + hh1 * W + sc2;
                b0 = pB[0]; b1 = pB[HW]; b2 = pB[2 * HW];
            }
            // fused AL loads for this thread's own pixel at this xi
            const int rr = half ? hh1 : hh0;
            const int ga = rr * W + w;
            float G0 = GhB[ga], G1 = GhB[HW + ga], G2 = GhB[2 * HW + ga];
            float Q0 = QhB[ga], Q1 = QhB[HW + ga], Q2 = QhB[2 * HW + ga];

            se4[t] = make_float4(a0, a1, a2, 0.f);
            if (has2) se4[t + 256] = make_float4(b0, b1, b2, 0.f);

            float xf = (float)x;
            float wtx = __expf(-SIGMA_SPACE * xf * xf);
            float gsum = (n0 + fmaf(tc0, G0, Q0))
                       + (n1 + fmaf(tc1, G1, Q1))
                       + (n2 + fmaf(tc2, G2, Q2));
            accAL = fmaf(wtx, gsum, accAL);
            __syncthreads();                   // staging visible

            unsigned mA = 0u, mB_ = 0u;
#pragma unroll
            for (int yi = 0; yi < KWIN; ++yi) {
                float4 o4 = se4[cb + yi];
                float g0 = o0c - o4.x, g1 = o1c - o4.y, g2 = o2c - o4.z;
                float sq = fmaf(g0, g0, fmaf(g1, g1, g2 * g2));
                unsigned bit = (sq < thr_l) ? 1u : 0u;
                if (yi < 21) mA = (mA << 1) | bit;
                else         mB_ = (mB_ << 1) | bit;
            }
            pmA[k] = mA; pmB[k] = mB_;
        }
    }

    // ---- phase 2: exact recompute of rare survivors from global (L2-resident) ----
#pragma unroll
    for (int k = 0; k < 3; ++k) {
        const int xi = split + 16 * k;
        if (xi < KWIN) {
            const int hh = reflect_idx(h + xi - WS, H);
#pragma unroll
            for (int wsel = 0; wsel < 2; ++wsel) {
                unsigned m_ = wsel ? pmB[k] : pmA[k];
                const int ybase = wsel ? 42 : 20;
                while (m_) {
                    int p = __builtin_ctz(m_);
                    m_ &= m_ - 1;
                    int yi = ybase - p;
                    int ww = reflect_idx(w + yi - WS, W);
                    int a = hh * W + ww;
                    float on0 = ob[a], on1 = ob[HW + a], on2 = ob[2 * HW + a];
                    float sn0 = sb[a], sn1 = sb[HW + a], sn2 = sb[2 * HW + a];
                    float g0 = o0c - on0, g1 = o1c - on1, g2 = o2c - on2;
                    float sq = fmaf(g0, g0, fmaf(g1, g1, g2 * g2));
                    float tt = -NEG_SC_LOG2E * sq;
                    float d0 = fabsf(s0c - sn0), d1 = fabsf(s1c - sn1), d2 = fabsf(s2c - sn2);
                    accS += __builtin_amdgcn_exp2f(fmaf(0.8f, __builtin_amdgcn_logf(d0), tt))
                          + __builtin_amdgcn_exp2f(fmaf(0.8f, __builtin_amdgcn_logf(d1), tt))
                          + __builtin_amdgcn_exp2f(fmaf(0.8f, __builtin_amdgcn_logf(d2), tt));
                }
            }
        }
    }

    float r = m * accAL + accS;
#pragma unroll
    for (int off = 32; off > 0; off >>= 1) r += __shfl_down(r, off, 64);
    if (lane == 0) red[wave] = r;
    __syncthreads();
    if (t == 0) atomicAdd(out, (red[0] + red[1] + red[2] + red[3]) * (1.0f / (float)NPIX));
}

extern "C" void kernel_launch(void* const* d_in, const int* in_sizes, int n_in,
                              void* d_out, int out_size, void* d_ws, size_t ws_size,
                              hipStream_t stream) {
    const float* orig   = (const float*)d_in[0];
    const float* smooth = (const float*)d_in[1];
    float* out = (float*)d_out;

    float* Gh  = (float*)d_ws;                   // 98304 floats
    float* Qh  = Gh + B * C * HW;                // 98304 floats
    float* msk = Qh + B * C * HW;                // 32768 floats

    prep_kernel<<<B * C * H, 384, 0, stream>>>(orig, smooth, Gh, Qh, msk, out);
    smooth_loss_kernel<<<B * (H / 2) * NSPLIT, 256, 0, stream>>>(orig, smooth, Gh, Qh, msk, out);
}

// Round 6
// 92.345 us; speedup vs baseline: 4.8527x; 4.8527x over previous
//
#include <hip/hip_runtime.h>
#include <math.h>

#define WS 21
#define KWIN 43            // 2*WS+1
#define H 128
#define W 128
#define B 2
#define C 3
#define HW (H * W)
#define CHW (C * H * W)
#define NPIX (B * H * W)   // 32768
#define SIGMA_SPACE (1.0f / 98.0f)
#define NSPLIT 16
#define EXT 170            // W + 2*WS
#define SQ_THR 0.15f       // skip pairs with wr < e^{-7.5} (validated rounds 3-5, absmax 0)
// wr * d^0.8 = exp2(0.8*log2(d) - 50*log2(e)*sq); 50*log2(e) = 72.13475204
#define NEG_SC_LOG2E 72.1347520445f
#define SG 17.509290f      // sum_{k=-21..21} exp(-k^2/98), fp64-derived

__device__ __forceinline__ int reflect_idx(int t, int n) {
    if (t < 0) t = -t;
    if (t > n - 1) t = 2 * (n - 1) - t;
    return t;
}

// ---------------- K1: H-pass conv (256 thr) + Sobel mask (128 thr) + out zero ----------------
__global__ __launch_bounds__(384)
void prep_kernel(const float* __restrict__ orig,
                 const float* __restrict__ smooth,
                 float* __restrict__ Gh, float* __restrict__ Qh,
                 float* __restrict__ mask, float* __restrict__ out) {
    __shared__ float row[EXT], rsq[EXT], wt[KWIN];
    const int bid = blockIdx.x;      // bc*128 + h ; bc = b*3+c
    const int h   = bid & 127;
    const int bc  = bid >> 7;
    const int t   = threadIdx.x;
    if (bid == 0 && t == 0) out[0] = 0.f;
    if (t < KWIN) { int k = t - WS; wt[t] = __expf(-SIGMA_SPACE * (float)(k * k)); }
    const float* src = smooth + bc * HW + h * W;
    if (t < EXT) {
        float v = src[reflect_idx(t - WS, W)];
        row[t] = v; rsq[t] = v * v;
    }
    __syncthreads();
    if (t < 256) {
        const int w = t & 127;
        const float* buf = (t < 128) ? row : rsq;
        float acc = 0.f;
#pragma unroll
        for (int y = 0; y < KWIN; ++y) acc = fmaf(wt[y], buf[w + y], acc);
        ((t < 128) ? Gh : Qh)[bid * W + w] = acc;
    } else if (bc == 0 || bc == 3) {
        const int b = bc / 3;
        const int w = t - 256;
        const float* ob = orig   + b * CHW;
        const float* sb = smooth + b * CHW;
        int hm = reflect_idx(h - 1, H), hp = reflect_idx(h + 1, H);
        int wm = reflect_idx(w - 1, W), wp = reflect_idx(w + 1, W);
        float eo = 0.f, es = 0.f;
#pragma unroll
        for (int c = 0; c < C; ++c) {
            const float* po = ob + c * HW;
            const float* ps = sb + c * HW;
            {
                float a00 = po[hm * W + wm], a01 = po[hm * W + w], a02 = po[hm * W + wp];
                float a10 = po[h  * W + wm],                        a12 = po[h  * W + wp];
                float a20 = po[hp * W + wm], a21 = po[hp * W + w], a22 = po[hp * W + wp];
                float gx = (a02 - a00) + 2.f * (a12 - a10) + (a22 - a20);
                float gy = (a20 - a00) + 2.f * (a21 - a01) + (a22 - a02);
                eo += sqrtf(gx * gx + gy * gy);
            }
            {
                float a00 = ps[hm * W + wm], a01 = ps[hm * W + w], a02 = ps[hm * W + wp];
                float a10 = ps[h  * W + wm],                        a12 = ps[h  * W + wp];
                float a20 = ps[hp * W + wm], a21 = ps[hp * W + w], a22 = ps[hp * W + wp];
                float gx = (a02 - a00) + 2.f * (a12 - a10) + (a22 - a20);
                float gy = (a20 - a00) + 2.f * (a21 - a01) + (a22 - a02);
                es += sqrtf(gx * gx + gy * gy);
            }
        }
        float m = ((eo < 20.0f) && ((es - eo) > 10.0f)) ? 1.0f : 0.0f;
        mask[(b << 14) + (h << 7) + w] = m;
    }
}

// ------- K2: branchless bitmask screen + fused AL + IMMEDIATE survivor consumption -------
// All per-xi state is scalar registers consumed in the same loop iteration:
// no private arrays -> no scratch (round-5 regression root cause).
__global__ __launch_bounds__(256, 4)
void smooth_loss_kernel(const float* __restrict__ orig,
                        const float* __restrict__ smooth,
                        const float* __restrict__ Gh, const float* __restrict__ Qh,
                        const float* __restrict__ mask,
                        float* __restrict__ out) {
    __shared__ float4 se4[340];     // [r*170 + e] = (o0,o1,o2,pad), reflection pre-applied
    __shared__ float red[4];

    const int t     = threadIdx.x;
    const int split = blockIdx.x & 15;
    const int rp    = (blockIdx.x >> 4) & 63;
    const int b     = blockIdx.x >> 10;
    const int h0    = rp * 2;
    const int w     = t & 127;
    const int half  = t >> 7;
    const int h     = h0 + half;
    const int lane  = t & 63;
    const int wave  = t >> 6;

    const float* ob  = orig   + b * CHW;
    const float* sb  = smooth + b * CHW;
    const float* GhB = Gh + b * 3 * HW;
    const float* QhB = Qh + b * 3 * HW;

    const int pix = (b << 14) + (h << 7) + w;
    const float m = mask[pix];
    const float thr_l = (m == 0.0f) ? SQ_THR : -1.0f;   // m==1 lanes never set bits

    float o0c, o1c, o2c, s0c, s1c, s2c;
    {
        int hw = h * W + w;
        o0c = ob[hw]; o1c = ob[HW + hw]; o2c = ob[2 * HW + hw];
        s0c = sb[hw]; s1c = sb[HW + hw]; s2c = sb[2 * HW + hw];
    }
    // AL constants (separable-Gaussian identity): per-channel s^2*Sg - 2s*Gh + Qh
    const float n0 = s0c * s0c * SG, n1 = s1c * s1c * SG, n2 = s2c * s2c * SG;
    const float tc0 = -2.f * s0c, tc1 = -2.f * s1c, tc2 = -2.f * s2c;

    // staging descriptors: element-1 = idx t, element-2 = idx t+256 (t<84); idx = r*170+e
    const int  e1r  = (t >= 170);
    const int  sc1  = reflect_idx((t - e1r * 170) - WS, W);
    const bool has2 = (t < 84);
    const int  sc2  = reflect_idx(t + 65, W);     // (t+256)-170-WS = t+65

    float accAL = 0.f, accS = 0.f;
    const int cb = half * EXT + w;

    for (int xi = split; xi < KWIN; xi += NSPLIT) {
        const int x   = xi - WS;
        const int hh0 = reflect_idx(h0 + x, H);
        const int hh1 = reflect_idx(h0 + 1 + x, H);
        const int rr  = half ? hh1 : hh0;          // reflect(h + x)

        __syncthreads();                   // previous screen done reading LDS
        // staging loads (orig only)
        const float* pA = ob + (e1r ? hh1 : hh0) * W + sc1;
        float a0 = pA[0], a1 = pA[HW], a2 = pA[2 * HW];
        float b0 = 0.f, b1 = 0.f, b2 = 0.f;
        if (has2) {
            const float* pB = ob + hh1 * W + sc2;
            b0 = pB[0]; b1 = pB[HW]; b2 = pB[2 * HW];
        }
        // fused AL loads for this thread's own pixel at this xi
        const int ga = rr * W + w;
        float G0 = GhB[ga], G1 = GhB[HW + ga], G2 = GhB[2 * HW + ga];
        float Q0 = QhB[ga], Q1 = QhB[HW + ga], Q2 = QhB[2 * HW + ga];

        se4[t] = make_float4(a0, a1, a2, 0.f);
        if (has2) se4[t + 256] = make_float4(b0, b1, b2, 0.f);

        float xf = (float)x;
        float wtx = __expf(-SIGMA_SPACE * xf * xf);
        float gsum = (n0 + fmaf(tc0, G0, Q0))
                   + (n1 + fmaf(tc1, G1, Q1))
                   + (n2 + fmaf(tc2, G2, Q2));
        accAL = fmaf(wtx, gsum, accAL);
        __syncthreads();                   // staging visible

        // ---- branchless screen: survivor bits in two scalar regs ----
        unsigned mA = 0u, mB_ = 0u;
#pragma unroll
        for (int yi = 0; yi < KWIN; ++yi) {
            float4 o4 = se4[cb + yi];
            float g0 = o0c - o4.x, g1 = o1c - o4.y, g2 = o2c - o4.z;
            float sq = fmaf(g0, g0, fmaf(g1, g1, g2 * g2));
            unsigned bit = (sq < thr_l) ? 1u : 0u;
            if (yi < 21) mA  = (mA  << 1) | bit;   // bit (20-yi)
            else         mB_ = (mB_ << 1) | bit;   // bit (42-yi)
        }

        // ---- immediate consumption: exact recompute of rare survivors (L2-resident) ----
        while (mA) {
            int p = __builtin_ctz(mA); mA &= mA - 1;
            int yi = 20 - p;
            int ww = reflect_idx(w + yi - WS, W);
            int a = rr * W + ww;
            float on0 = ob[a], on1 = ob[HW + a], on2 = ob[2 * HW + a];
            float sn0 = sb[a], sn1 = sb[HW + a], sn2 = sb[2 * HW + a];
            float g0 = o0c - on0, g1 = o1c - on1, g2 = o2c - on2;
            float sq = fmaf(g0, g0, fmaf(g1, g1, g2 * g2));
            float tt = -NEG_SC_LOG2E * sq;
            float d0 = fabsf(s0c - sn0), d1 = fabsf(s1c - sn1), d2 = fabsf(s2c - sn2);
            accS += __builtin_amdgcn_exp2f(fmaf(0.8f, __builtin_amdgcn_logf(d0), tt))
                  + __builtin_amdgcn_exp2f(fmaf(0.8f, __builtin_amdgcn_logf(d1), tt))
                  + __builtin_amdgcn_exp2f(fmaf(0.8f, __builtin_amdgcn_logf(d2), tt));
        }
        while (mB_) {
            int p = __builtin_ctz(mB_); mB_ &= mB_ - 1;
            int yi = 42 - p;
            int ww = reflect_idx(w + yi - WS, W);
            int a = rr * W + ww;
            float on0 = ob[a], on1 = ob[HW + a], on2 = ob[2 * HW + a];
            float sn0 = sb[a], sn1 = sb[HW + a], sn2 = sb[2 * HW + a];
            float g0 = o0c - on0, g1 = o1c - on1, g2 = o2c - on2;
            float sq = fmaf(g0, g0, fmaf(g1, g1, g2 * g2));
            float tt = -NEG_SC_LOG2E * sq;
            float d0 = fabsf(s0c - sn0), d1 = fabsf(s1c - sn1), d2 = fabsf(s2c - sn2);
            accS += __builtin_amdgcn_exp2f(fmaf(0.8f, __builtin_amdgcn_logf(d0), tt))
                  + __builtin_amdgcn_exp2f(fmaf(0.8f, __builtin_amdgcn_logf(d1), tt))
                  + __builtin_amdgcn_exp2f(fmaf(0.8f, __builtin_amdgcn_logf(d2), tt));
        }
    }

    float r = m * accAL + accS;
#pragma unroll
    for (int off = 32; off > 0; off >>= 1) r += __shfl_down(r, off, 64);
    if (lane == 0) red[wave] = r;
    __syncthreads();
    if (t == 0) atomicAdd(out, (red[0] + red[1] + red[2] + red[3]) * (1.0f / (float)NPIX));
}

extern "C" void kernel_launch(void* const* d_in, const int* in_sizes, int n_in,
                              void* d_out, int out_size, void* d_ws, size_t ws_size,
                              hipStream_t stream) {
    const float* orig   = (const float*)d_in[0];
    const float* smooth = (const float*)d_in[1];
    float* out = (float*)d_out;

    float* Gh  = (float*)d_ws;                   // 98304 floats
    float* Qh  = Gh + B * C * HW;                // 98304 floats
    float* msk = Qh + B * C * HW;                // 32768 floats

    prep_kernel<<<B * C * H, 384, 0, stream>>>(orig, smooth, Gh, Qh, msk, out);
    smooth_loss_kernel<<<B * (H / 2) * NSPLIT, 256, 0, stream>>>(orig, smooth, Gh, Qh, msk, out);
}

// Round 7
// 90.001 us; speedup vs baseline: 4.9791x; 1.0260x over previous
//
#include <hip/hip_runtime.h>
#include <math.h>

#define WS 21
#define KWIN 43            // 2*WS+1
#define H 128
#define W 128
#define B 2
#define C 3
#define HW (H * W)
#define CHW (C * H * W)
#define NPIX (B * H * W)   // 32768
#define SIGMA_SPACE (1.0f / 98.0f)
#define NSPLIT 16
#define EXT 170            // W + 2*WS
#define SQ_THR_FP16 0.17f  // fp16-screen threshold: 0.15 + margin for half rounding
// wr * d^0.8 = exp2(0.8*log2(d) - 50*log2(e)*sq); 50*log2(e) = 72.13475204
#define NEG_SC_LOG2E 72.1347520445f
#define SG 17.509290f      // sum_{k=-21..21} exp(-k^2/98), fp64-derived

typedef _Float16 h2_t __attribute__((ext_vector_type(2)));

__device__ __forceinline__ int reflect_idx(int t, int n) {
    if (t < 0) t = -t;
    if (t > n - 1) t = 2 * (n - 1) - t;
    return t;
}

// ---------------- K1: H-pass conv (256 thr) + Sobel mask (128 thr) + out zero ----------------
__global__ __launch_bounds__(384)
void prep_kernel(const float* __restrict__ orig,
                 const float* __restrict__ smooth,
                 float* __restrict__ Gh, float* __restrict__ Qh,
                 float* __restrict__ mask, float* __restrict__ out) {
    __shared__ float row[EXT], rsq[EXT], wt[KWIN];
    const int bid = blockIdx.x;      // bc*128 + h ; bc = b*3+c
    const int h   = bid & 127;
    const int bc  = bid >> 7;
    const int t   = threadIdx.x;
    if (bid == 0 && t == 0) out[0] = 0.f;
    if (t < KWIN) { int k = t - WS; wt[t] = __expf(-SIGMA_SPACE * (float)(k * k)); }
    const float* src = smooth + bc * HW + h * W;
    if (t < EXT) {
        float v = src[reflect_idx(t - WS, W)];
        row[t] = v; rsq[t] = v * v;
    }
    __syncthreads();
    if (t < 256) {
        const int w = t & 127;
        const float* buf = (t < 128) ? row : rsq;
        float acc = 0.f;
#pragma unroll
        for (int y = 0; y < KWIN; ++y) acc = fmaf(wt[y], buf[w + y], acc);
        ((t < 128) ? Gh : Qh)[bid * W + w] = acc;
    } else if (bc == 0 || bc == 3) {
        const int b = bc / 3;
        const int w = t - 256;
        const float* ob = orig   + b * CHW;
        const float* sb = smooth + b * CHW;
        int hm = reflect_idx(h - 1, H), hp = reflect_idx(h + 1, H);
        int wm = reflect_idx(w - 1, W), wp = reflect_idx(w + 1, W);
        float eo = 0.f, es = 0.f;
#pragma unroll
        for (int c = 0; c < C; ++c) {
            const float* po = ob + c * HW;
            const float* ps = sb + c * HW;
            {
                float a00 = po[hm * W + wm], a01 = po[hm * W + w], a02 = po[hm * W + wp];
                float a10 = po[h  * W + wm],                        a12 = po[h  * W + wp];
                float a20 = po[hp * W + wm], a21 = po[hp * W + w], a22 = po[hp * W + wp];
                float gx = (a02 - a00) + 2.f * (a12 - a10) + (a22 - a20);
                float gy = (a20 - a00) + 2.f * (a21 - a01) + (a22 - a02);
                eo += sqrtf(gx * gx + gy * gy);
            }
            {
                float a00 = ps[hm * W + wm], a01 = ps[hm * W + w], a02 = ps[hm * W + wp];
                float a10 = ps[h  * W + wm],                        a12 = ps[h  * W + wp];
                float a20 = ps[hp * W + wm], a21 = ps[hp * W + w], a22 = ps[hp * W + wp];
                float gx = (a02 - a00) + 2.f * (a12 - a10) + (a22 - a20);
                float gy = (a20 - a00) + 2.f * (a21 - a01) + (a22 - a02);
                es += sqrtf(gx * gx + gy * gy);
            }
        }
        float m = ((eo < 20.0f) && ((es - eo) > 10.0f)) ? 1.0f : 0.0f;
        mask[(b << 14) + (h << 7) + w] = m;
    }
}

// ------- K2: fp16-packed b64 screen (LDS-BW fix) + fused AL + immediate consumption -------
__global__ __launch_bounds__(256, 4)
void smooth_loss_kernel(const float* __restrict__ orig,
                        const float* __restrict__ smooth,
                        const float* __restrict__ Gh, const float* __restrict__ Qh,
                        const float* __restrict__ mask,
                        float* __restrict__ out) {
    __shared__ uint2 se[340];       // [r*170 + e] = fp16 (o0,o1),(o2,0); reflection pre-applied
    __shared__ float red[4];

    const int t     = threadIdx.x;
    const int split = blockIdx.x & 15;
    const int rp    = (blockIdx.x >> 4) & 63;
    const int b     = blockIdx.x >> 10;
    const int h0    = rp * 2;
    const int w     = t & 127;
    const int half  = t >> 7;
    const int h     = h0 + half;
    const int lane  = t & 63;
    const int wave  = t >> 6;

    const float* ob  = orig   + b * CHW;
    const float* sb  = smooth + b * CHW;
    const float* GhB = Gh + b * 3 * HW;
    const float* QhB = Qh + b * 3 * HW;

    const int pix = (b << 14) + (h << 7) + w;
    const float m = mask[pix];
    const float thr_l = (m == 0.0f) ? SQ_THR_FP16 : -1.0f;   // m==1 lanes never set bits

    float o0c, o1c, o2c, s0c, s1c, s2c;
    {
        int hw = h * W + w;
        o0c = ob[hw]; o1c = ob[HW + hw]; o2c = ob[2 * HW + hw];
        s0c = sb[hw]; s1c = sb[HW + hw]; s2c = sb[2 * HW + hw];
    }
    const h2_t c01h = { (_Float16)o0c, (_Float16)o1c };
    const h2_t c2xh = { (_Float16)o2c, (_Float16)0.f };

    // AL constants (separable-Gaussian identity): per-channel s^2*Sg - 2s*Gh + Qh
    const float n0 = s0c * s0c * SG, n1 = s1c * s1c * SG, n2 = s2c * s2c * SG;
    const float tc0 = -2.f * s0c, tc1 = -2.f * s1c, tc2 = -2.f * s2c;

    // staging descriptors: element-1 = idx t, element-2 = idx t+256 (t<84); idx = r*170+e
    const int  e1r  = (t >= 170);
    const int  sc1  = reflect_idx((t - e1r * 170) - WS, W);
    const bool has2 = (t < 84);
    const int  sc2  = reflect_idx(t + 65, W);     // (t+256)-170-WS = t+65

    float accAL = 0.f, accS = 0.f;
    const int cb = half * EXT + w;

    for (int xi = split; xi < KWIN; xi += NSPLIT) {
        const int x   = xi - WS;
        const int hh0 = reflect_idx(h0 + x, H);
        const int hh1 = reflect_idx(h0 + 1 + x, H);
        const int rr  = half ? hh1 : hh0;          // reflect(h + x)

        __syncthreads();                   // previous screen done reading LDS
        // staging loads (orig only), convert to packed fp16
        const float* pA = ob + (e1r ? hh1 : hh0) * W + sc1;
        float a0 = pA[0], a1 = pA[HW], a2 = pA[2 * HW];
        float b0 = 0.f, b1 = 0.f, b2 = 0.f;
        if (has2) {
            const float* pB = ob + hh1 * W + sc2;
            b0 = pB[0]; b1 = pB[HW]; b2 = pB[2 * HW];
        }
        // fused AL loads for this thread's own pixel at this xi
        const int ga = rr * W + w;
        float G0 = GhB[ga], G1 = GhB[HW + ga], G2 = GhB[2 * HW + ga];
        float Q0 = QhB[ga], Q1 = QhB[HW + ga], Q2 = QhB[2 * HW + ga];

        {
            h2_t pa01 = { (_Float16)a0, (_Float16)a1 };
            h2_t pa2x = { (_Float16)a2, (_Float16)0.f };
            se[t] = make_uint2(__builtin_bit_cast(unsigned, pa01),
                               __builtin_bit_cast(unsigned, pa2x));
            if (has2) {
                h2_t pb01 = { (_Float16)b0, (_Float16)b1 };
                h2_t pb2x = { (_Float16)b2, (_Float16)0.f };
                se[t + 256] = make_uint2(__builtin_bit_cast(unsigned, pb01),
                                         __builtin_bit_cast(unsigned, pb2x));
            }
        }

        float xf = (float)x;
        float wtx = __expf(-SIGMA_SPACE * xf * xf);
        float gsum = (n0 + fmaf(tc0, G0, Q0))
                   + (n1 + fmaf(tc1, G1, Q1))
                   + (n2 + fmaf(tc2, G2, Q2));
        accAL = fmaf(wtx, gsum, accAL);
        __syncthreads();                   // staging visible

        // ---- branchless fp16 screen: survivor bits in two scalar regs ----
        unsigned mA = 0u, mB_ = 0u;
#pragma unroll
        for (int yi = 0; yi < KWIN; ++yi) {
            uint2 vv = se[cb + yi];
            h2_t a01 = __builtin_bit_cast(h2_t, vv.x);
            h2_t a2x = __builtin_bit_cast(h2_t, vv.y);
            h2_t d01 = c01h - a01;
            h2_t d2x = c2xh - a2x;
            float sq = __builtin_amdgcn_fdot2(d01, d01,
                        __builtin_amdgcn_fdot2(d2x, d2x, 0.f, false), false);
            unsigned bit = (sq < thr_l) ? 1u : 0u;
            if (yi < 21) mA  = (mA  << 1) | bit;   // bit (20-yi)
            else         mB_ = (mB_ << 1) | bit;   // bit (42-yi)
        }

        // ---- immediate consumption: exact fp32 recompute of rare survivors (L2-resident) ----
        while (mA) {
            int p = __builtin_ctz(mA); mA &= mA - 1;
            int yi = 20 - p;
            int ww = reflect_idx(w + yi - WS, W);
            int a = rr * W + ww;
            float on0 = ob[a], on1 = ob[HW + a], on2 = ob[2 * HW + a];
            float sn0 = sb[a], sn1 = sb[HW + a], sn2 = sb[2 * HW + a];
            float g0 = o0c - on0, g1 = o1c - on1, g2 = o2c - on2;
            float sq = fmaf(g0, g0, fmaf(g1, g1, g2 * g2));
            float tt = -NEG_SC_LOG2E * sq;
            float d0 = fabsf(s0c - sn0), d1 = fabsf(s1c - sn1), d2 = fabsf(s2c - sn2);
            accS += __builtin_amdgcn_exp2f(fmaf(0.8f, __builtin_amdgcn_logf(d0), tt))
                  + __builtin_amdgcn_exp2f(fmaf(0.8f, __builtin_amdgcn_logf(d1), tt))
                  + __builtin_amdgcn_exp2f(fmaf(0.8f, __builtin_amdgcn_logf(d2), tt));
        }
        while (mB_) {
            int p = __builtin_ctz(mB_); mB_ &= mB_ - 1;
            int yi = 42 - p;
            int ww = reflect_idx(w + yi - WS, W);
            int a = rr * W + ww;
            float on0 = ob[a], on1 = ob[HW + a], on2 = ob[2 * HW + a];
            float sn0 = sb[a], sn1 = sb[HW + a], sn2 = sb[2 * HW + a];
            float g0 = o0c - on0, g1 = o1c - on1, g2 = o2c - on2;
            float sq = fmaf(g0, g0, fmaf(g1, g1, g2 * g2));
            float tt = -NEG_SC_LOG2E * sq;
            float d0 = fabsf(s0c - sn0), d1 = fabsf(s1c - sn1), d2 = fabsf(s2c - sn2);
            accS += __builtin_amdgcn_exp2f(fmaf(0.8f, __builtin_amdgcn_logf(d0), tt))
                  + __builtin_amdgcn_exp2f(fmaf(0.8f, __builtin_amdgcn_logf(d1), tt))
                  + __builtin_amdgcn_exp2f(fmaf(0.8f, __builtin_amdgcn_logf(d2), tt));
        }
    }

    float r = m * accAL + accS;
#pragma unroll
    for (int off = 32; off > 0; off >>= 1) r += __shfl_down(r, off, 64);
    if (lane == 0) red[wave] = r;
    __syncthreads();
    if (t == 0) atomicAdd(out, (red[0] + red[1] + red[2] + red[3]) * (1.0f / (float)NPIX));
}

extern "C" void kernel_launch(void* const* d_in, const int* in_sizes, int n_in,
                              void* d_out, int out_size, void* d_ws, size_t ws_size,
                              hipStream_t stream) {
    const float* orig   = (const float*)d_in[0];
    const float* smooth = (const float*)d_in[1];
    float* out = (float*)d_out;

    float* Gh  = (float*)d_ws;                   // 98304 floats
    float* Qh  = Gh + B * C * HW;                // 98304 floats
    float* msk = Qh + B * C * HW;                // 32768 floats

    prep_kernel<<<B * C * H, 384, 0, stream>>>(orig, smooth, Gh, Qh, msk, out);
    smooth_loss_kernel<<<B * (H / 2) * NSPLIT, 256, 0, stream>>>(orig, smooth, Gh, Qh, msk, out);
}